// Round 3
// baseline (81.945 us; speedup 1.0000x reference)
//
#include <hip/hip_runtime.h>

#define NCH 64
#define IMG 256
#define KSEL 8
#define CAP 64           // max candidates per row (mean ~12, max over 512 rows ~30)
#define FPAD 17          // float4 per candidate slot (68 floats; breaks pow2 banks)

// ---- single-block binning: bucket points into per-(b,row) candidate lists ----
__global__ __launch_bounds__(1024) void bin_points_kernel(
    const float* __restrict__ pts3D,  // [B, P, 3]
    int* __restrict__ cnts,           // [B*IMG]
    float4* __restrict__ lst,         // [B*IMG][CAP] (x,y,z,idx-bits)
    int P, int B)
{
    const int tid = threadIdx.x;
    const int nrow = B * IMG;
    for (int i = tid; i < nrow; i += 1024) cnts[i] = 0;
    __syncthreads();   // single block: orders the zeroing before atomics

    const float r_ndc = (1.5f / (float)IMG) * 2.0f;
    const float r2    = r_ndc * r_ndc;

    const int total = B * P;
    for (int t = tid; t < total; t += 1024) {
        int b = t / P, p = t - b * P;
        const float* pp = pts3D + ((size_t)b * P + p) * 3;
        float px = -pp[0];
        float py = -pp[1];
        float pz =  pp[2];
        if (pz <= 0.0f) continue;
        // row of zero dy: h_c = (1-py)*H/2 - 0.5 ; radius = 1.5 rows
        float hc = (1.0f - py) * ((float)IMG * 0.5f) - 0.5f;
        int h0 = max((int)floorf(hc - 1.5f) - 1, 0);
        int h1 = min((int)ceilf (hc + 1.5f) + 1, IMG - 1);
        for (int h = h0; h <= h1; ++h) {
            float yf = 1.0f - (2.0f * (float)h + 1.0f) / (float)IMG;
            float dy = yf - py;
            if (dy * dy <= r2) {        // identical fp32 test as before
                int row = b * IMG + h;
                int slot = atomicAdd(&cnts[row], 1);
                if (slot < CAP)
                    lst[(size_t)row * CAP + slot] =
                        make_float4(px, py, pz, __int_as_float(p));
            }
        }
    }
}

__global__ __launch_bounds__(256) void raster_blend_kernel(
    const int* __restrict__ cnts,
    const float4* __restrict__ lst,
    const float* __restrict__ src,    // [B, C, P]
    float* __restrict__ out,          // [B, C, H, W]
    int P)
{
    const int h = blockIdx.x;
    const int b = blockIdx.y;
    const int w = threadIdx.x;
    const int HW = IMG * IMG;

    const float r_ndc  = (1.5f / (float)IMG) * 2.0f;
    const float r2     = r_ndc * r_ndc;
    const float inv_r2 = 1.0f / r2;

    const float yf = 1.0f - (2.0f * (float)h + 1.0f) / (float)IMG;
    const float xf = 1.0f - (2.0f * (float)w + 1.0f) / (float)IMG;

    __shared__ float cx[CAP], cy[CAP], cz[CAP];
    __shared__ int   ci[CAP];
    __shared__ __align__(16) float featS[CAP * FPAD * 4];  // 17408 B

    const int row = b * IMG + h;
    const int n = min(cnts[row], CAP);

    if (w < n) {
        float4 e = lst[(size_t)row * CAP + w];
        cx[w] = e.x; cy[w] = e.y; cz[w] = e.z; ci[w] = __float_as_int(e.w);
    }
    __syncthreads();

    // ---- stage candidate features from src (scattered; ~n*64 dwords) ----
    const float* sb = src + (size_t)b * NCH * P;
    for (int t = w; t < n * NCH; t += 256) {
        int j = t >> 6;          // candidate slot (one j per wave-iter)
        int c = t & 63;          // channel
        featS[j * (FPAD * 4) + c] = sb[(size_t)c * P + ci[j]];
    }

    // ---- per-pixel K-nearest-in-z selection (register insertion) ----
    const float SENT = 1e30f;
    float zb[KSEL], db[KSEL];
    int   jb[KSEL];
#pragma unroll
    for (int s = 0; s < KSEL; ++s) { zb[s] = SENT; db[s] = 0.0f; jb[s] = 0; }

    for (int j = 0; j < n; ++j) {
        float dx = xf - cx[j];
        float dy = yf - cy[j];
        float d2 = fmaf(dx, dx, dy * dy);
        float z  = cz[j];
        if (d2 <= r2 && z < zb[KSEL - 1]) {
            float carz = z, card = d2;
            int   carj = j;
#pragma unroll
            for (int s = 0; s < KSEL; ++s) {
                if (carz < zb[s]) {
                    float tz = zb[s]; zb[s] = carz; carz = tz;
                    float td = db[s]; db[s] = card; card = td;
                    int   tj = jb[s]; jb[s] = carj; carj = tj;
                }
            }
        }
    }

    // ---- alpha-composite weights (front-to-back) ----
    float wk[KSEL];
    bool  vk[KSEL];
    float T = 1.0f;
#pragma unroll
    for (int s = 0; s < KSEL; ++s) {
        bool valid = zb[s] < 1e29f;
        vk[s] = valid;
        float dn = db[s] * inv_r2;
        dn = fminf(fmaxf(dn, 0.001f), 1.0f);
        float a = 1.0f - sqrtf(dn);
        a = valid ? a : 0.0f;
        wk[s] = a * T;
        T *= (1.0f - a);
    }

    __syncthreads();   // feature staging complete

    // ---- channel accumulation from LDS feature cache ----
    float4 acc[NCH / 4];
#pragma unroll
    for (int c4 = 0; c4 < NCH / 4; ++c4) acc[c4] = make_float4(0.f, 0.f, 0.f, 0.f);

    const float4* fv = (const float4*)featS;
#pragma unroll
    for (int k = 0; k < KSEL; ++k) {
        if (__any(vk[k])) {
            float wv = wk[k];                     // 0 for invalid lanes
            const float4* fp = fv + jb[k] * FPAD; // jb=0 safe
#pragma unroll
            for (int c4 = 0; c4 < NCH / 4; ++c4) {
                float4 f = fp[c4];
                acc[c4].x = fmaf(wv, f.x, acc[c4].x);
                acc[c4].y = fmaf(wv, f.y, acc[c4].y);
                acc[c4].z = fmaf(wv, f.z, acc[c4].z);
                acc[c4].w = fmaf(wv, f.w, acc[c4].w);
            }
        }
    }

    // ---- coalesced stores ----
    float* op = out + (size_t)b * NCH * HW + (size_t)h * IMG + w;
#pragma unroll
    for (int c4 = 0; c4 < NCH / 4; ++c4) {
        op[(size_t)(4 * c4 + 0) * HW] = acc[c4].x;
        op[(size_t)(4 * c4 + 1) * HW] = acc[c4].y;
        op[(size_t)(4 * c4 + 2) * HW] = acc[c4].z;
        op[(size_t)(4 * c4 + 3) * HW] = acc[c4].w;
    }
}

extern "C" void kernel_launch(void* const* d_in, const int* in_sizes, int n_in,
                              void* d_out, int out_size, void* d_ws, size_t ws_size,
                              hipStream_t stream) {
    const float* pts3D = (const float*)d_in[0];
    const float* src   = (const float*)d_in[1];
    float* out = (float*)d_out;

    const int B = out_size / (NCH * IMG * IMG);
    const int P = in_sizes[0] / (3 * B);

    int*    cnts = (int*)d_ws;                          // [B*IMG]
    float4* lst  = (float4*)((char*)d_ws + 4096);       // [B*IMG][CAP]

    bin_points_kernel<<<1, 1024, 0, stream>>>(pts3D, cnts, lst, P, B);

    dim3 grid(IMG, B, 1);
    dim3 block(256, 1, 1);
    raster_blend_kernel<<<grid, block, 0, stream>>>(cnts, lst, src, out, P);
}

// Round 4
// 72.745 us; speedup vs baseline: 1.1265x; 1.1265x over previous
//
#include <hip/hip_runtime.h>

#define NCH 64
#define IMG 256
#define KSEL 8
#define CAP 64           // max candidates per row (mean ~13, max over 512 rows ~26)
#define FPAD 17          // float4 per candidate slot (68 floats; breaks pow2 banks)

__global__ __launch_bounds__(256) void raster_blend_kernel(
    const float* __restrict__ pts3D,  // [B, P, 3]
    const float* __restrict__ src,    // [B, C, P]
    float* __restrict__ out,          // [B, C, H, W]
    int P)
{
    const int h = blockIdx.x;
    const int b = blockIdx.y;
    const int w = threadIdx.x;
    const int HW = IMG * IMG;

    const float r_ndc  = (1.5f / (float)IMG) * 2.0f;
    const float r2     = r_ndc * r_ndc;
    const float inv_r2 = 1.0f / r2;

    const float yf = 1.0f - (2.0f * (float)h + 1.0f) / (float)IMG;
    const float xf = 1.0f - (2.0f * (float)w + 1.0f) / (float)IMG;

    __shared__ float cx[CAP], cy[CAP], cz[CAP];
    __shared__ int   ci[CAP];
    __shared__ int   cnt;
    __shared__ __align__(16) float featS[CAP * FPAD * 4];  // 17408 B
    if (w == 0) cnt = 0;
    __syncthreads();

    // ---- Phase 1: row-filter all points into LDS candidate list ----
    const float* pb = pts3D + (size_t)b * P * 3;
    for (int p = w; p < P; p += 256) {
        float px = -pb[p * 3 + 0];
        float py = -pb[p * 3 + 1];
        float pz =  pb[p * 3 + 2];
        float dy = yf - py;
        if (dy * dy <= r2 && pz > 0.0f) {
            int slot = atomicAdd(&cnt, 1);
            if (slot < CAP) {
                cx[slot] = px;
                cy[slot] = py;
                cz[slot] = pz;
                ci[slot] = p;
            }
        }
    }
    __syncthreads();
    const int n = min(cnt, CAP);

    // ---- Phase 1b: stage candidate features straight from src ----
    // per wave-iter: j fixed, c = lane -> 4KB-strided gather, ~n*64 dwords total
    const float* sb = src + (size_t)b * NCH * P;
    for (int t = w; t < n * NCH; t += 256) {
        int j = t >> 6;
        int c = t & 63;
        featS[j * (FPAD * 4) + c] = sb[(size_t)c * P + ci[j]];
    }

    // ---- Phase 2: per-pixel K-nearest-in-z selection (register insertion) ----
    const float SENT = 1e30f;
    float zb[KSEL], db[KSEL];
    int   jb[KSEL];
#pragma unroll
    for (int s = 0; s < KSEL; ++s) { zb[s] = SENT; db[s] = 0.0f; jb[s] = 0; }

    for (int j = 0; j < n; ++j) {
        float dx = xf - cx[j];
        float dy = yf - cy[j];
        float d2 = fmaf(dx, dx, dy * dy);
        float z  = cz[j];
        if (d2 <= r2 && z < zb[KSEL - 1]) {
            float carz = z, card = d2;
            int   carj = j;
#pragma unroll
            for (int s = 0; s < KSEL; ++s) {
                if (carz < zb[s]) {
                    float tz = zb[s]; zb[s] = carz; carz = tz;
                    float td = db[s]; db[s] = card; card = td;
                    int   tj = jb[s]; jb[s] = carj; carj = tj;
                }
            }
        }
    }

    // ---- alpha-composite weights (front-to-back) ----
    float wk[KSEL];
    bool  vk[KSEL];
    float T = 1.0f;
#pragma unroll
    for (int s = 0; s < KSEL; ++s) {
        bool valid = zb[s] < 1e29f;
        vk[s] = valid;
        float dn = db[s] * inv_r2;
        dn = fminf(fmaxf(dn, 0.001f), 1.0f);
        float a = 1.0f - sqrtf(dn);
        a = valid ? a : 0.0f;
        wk[s] = a * T;
        T *= (1.0f - a);
    }

    __syncthreads();   // feature staging complete

    // ---- channel accumulation from LDS feature cache ----
    float4 acc[NCH / 4];
#pragma unroll
    for (int c4 = 0; c4 < NCH / 4; ++c4) acc[c4] = make_float4(0.f, 0.f, 0.f, 0.f);

    const float4* fv = (const float4*)featS;
#pragma unroll
    for (int k = 0; k < KSEL; ++k) {
        if (__any(vk[k])) {
            float wv = wk[k];                     // 0 for invalid lanes
            const float4* fp = fv + jb[k] * FPAD; // jb=0 safe
#pragma unroll
            for (int c4 = 0; c4 < NCH / 4; ++c4) {
                float4 f = fp[c4];
                acc[c4].x = fmaf(wv, f.x, acc[c4].x);
                acc[c4].y = fmaf(wv, f.y, acc[c4].y);
                acc[c4].z = fmaf(wv, f.z, acc[c4].z);
                acc[c4].w = fmaf(wv, f.w, acc[c4].w);
            }
        }
    }

    // ---- coalesced stores (256 B contiguous per wave-instruction) ----
    float* op = out + (size_t)b * NCH * HW + (size_t)h * IMG + w;
#pragma unroll
    for (int c4 = 0; c4 < NCH / 4; ++c4) {
        op[(size_t)(4 * c4 + 0) * HW] = acc[c4].x;
        op[(size_t)(4 * c4 + 1) * HW] = acc[c4].y;
        op[(size_t)(4 * c4 + 2) * HW] = acc[c4].z;
        op[(size_t)(4 * c4 + 3) * HW] = acc[c4].w;
    }
}

extern "C" void kernel_launch(void* const* d_in, const int* in_sizes, int n_in,
                              void* d_out, int out_size, void* d_ws, size_t ws_size,
                              hipStream_t stream) {
    const float* pts3D = (const float*)d_in[0];
    const float* src   = (const float*)d_in[1];
    float* out = (float*)d_out;

    const int B = out_size / (NCH * IMG * IMG);
    const int P = in_sizes[0] / (3 * B);

    dim3 grid(IMG, B, 1);
    dim3 block(256, 1, 1);
    raster_blend_kernel<<<grid, block, 0, stream>>>(pts3D, src, out, P);
}